// Round 2
// baseline (335.313 us; speedup 1.0000x reference)
//
#include <hip/hip_runtime.h>

// Problem constants (from reference):
//   B=1024 batches, S=200 seq, D=64 dim, C=256 clusters
// Outputs (concat in d_out, all read back as float32):
//   out[0] cluster_emb  [B,C,D] = 16,777,216 f32
//   out[1] cluster_mask [B,C,S] = 52,428,800 f32 (0.0/1.0 values)
//
// Role-split blocks, 3 per batch:
//   role 0,1: stream one half of cluster_mask[b] (store-bound, nt vec4).
//   role 2:   stage x[b] (51.2 KB) into LDS, build counting-sort CSR,
//             accumulate per-cluster means from LDS (~120cy latency chain
//             instead of ~900cy HBM chain), unrolled x2 across clusters.
// LDS 56 KB -> 2 blocks/CU. Store saturation needs only ~3 waves/CU
// (fill kernel: 6.2 TB/s at 9.7% occupancy), so mask role is unharmed.
#define NB 1024
#define NS 200
#define ND 64
#define NC 256

typedef float v4f __attribute__((ext_vector_type(4)));

__global__ __launch_bounds__(256) void s3rec_cluster_kernel(
    const float* __restrict__ x,       // [B,S,D]
    const int*   __restrict__ labels,  // [B,S]
    const int*   __restrict__ amask,   // [B,S]
    float* __restrict__ out_emb,       // [B,C,D]
    float* __restrict__ out_mask)      // [B,C,S]
{
    __shared__ __align__(16) float s_x[NS * ND];   // 51200 B staged x[b]
    __shared__ __align__(16) int s_lab[NS];        // label if masked else -1
    __shared__ int   s_cnt[NC];
    __shared__ int   s_off[NC];
    __shared__ float s_inv[NC];
    __shared__ int   s_list[NS];                   // seq idx grouped by cluster
    __shared__ int   s_part[4];

    const int role = blockIdx.x % 3;   // 0,1 = mask halves; 2 = emb
    const int b    = blockIdx.x / 3;
    const int t    = threadIdx.x;

    // --- stage labels packed with mask ---
    for (int i = t; i < NS; i += 256) {
        const int l = labels[b * NS + i];
        const int m = amask [b * NS + i];
        s_lab[i] = (m != 0) ? l : -1;
    }

    if (role < 2) {
        // ---------------- mask writer: half of [C,S] = 6400 vec4 ----------
        __syncthreads();
        v4f* om4 = reinterpret_cast<v4f*>(out_mask + (size_t)b * (NC * NS));
        const int i4lo = role * 6400;
        #pragma unroll 5
        for (int k = 0; k < 25; ++k) {
            const int i4 = i4lo + k * 256 + t;
            const int c  = i4 / 50;
            const int s0 = (i4 - c * 50) * 4;      // 16B aligned
            const int4 lv = *reinterpret_cast<const int4*>(&s_lab[s0]);
            v4f v;
            v.x = (lv.x == c) ? 1.0f : 0.0f;
            v.y = (lv.y == c) ? 1.0f : 0.0f;
            v.z = (lv.z == c) ? 1.0f : 0.0f;
            v.w = (lv.w == c) ? 1.0f : 0.0f;
            __builtin_nontemporal_store(v, &om4[i4]);
        }
        return;
    }

    // ---------------- emb computer ---------------------------------------
    // 0) stage x[b] into LDS: 3200 independent vec4 copies (pipelined).
    const float* xb = x + (size_t)b * NS * ND;
    {
        const v4f* xb4 = reinterpret_cast<const v4f*>(xb);
        v4f* sx4 = reinterpret_cast<v4f*>(s_x);
        for (int i4 = t; i4 < (NS * ND) / 4; i4 += 256) sx4[i4] = xb4[i4];
    }

    // 1) histogram (t indexes clusters exactly: NC == 256)
    s_cnt[t] = 0;
    __syncthreads();
    if (t < NS) {
        const int l = s_lab[t];
        if (l >= 0) atomicAdd(&s_cnt[l], 1);
    }
    __syncthreads();

    // 2) inverse counts + exclusive prefix scan over 256 counts
    const int lane = t & 63;
    const int w    = t >> 6;
    const int cnt  = s_cnt[t];
    s_inv[t] = (cnt > 0) ? (1.0f / (float)cnt) : 0.0f;

    int v = cnt;                                  // wave-inclusive scan
    #pragma unroll
    for (int d = 1; d < 64; d <<= 1) {
        const int n = __shfl_up(v, d, 64);
        if (lane >= d) v += n;
    }
    if (lane == 63) s_part[w] = v;
    __syncthreads();
    int base = 0;
    for (int i = 0; i < w; ++i) base += s_part[i];
    s_off[t] = base + v - cnt;                    // exclusive offset
    __syncthreads();

    // 3) deterministic scatter: rank = #earlier same-label entries, so each
    //    cluster's list is ascending in s (matches reference sum order).
    if (t < NS) {
        const int L = s_lab[t];
        if (L >= 0) {
            int r = 0;
            for (int s2 = 0; s2 < t; ++s2) r += (s_lab[s2] == L) ? 1 : 0;
            s_list[s_off[L] + r] = t;
        }
    }
    __syncthreads();

    // 4) accumulate from LDS, 2 clusters in flight per wave (c wave-uniform,
    //    lane = d). Row read = 64 consecutive dwords -> 2 lanes/bank, free.
    float* oe = out_emb + (size_t)b * (NC * ND);
    for (int cc = 0; cc < 64; cc += 2) {
        const int c0 = w * 64 + cc;
        const int c1 = c0 + 1;
        const int n0 = s_cnt[c0], o0 = s_off[c0];
        const int n1 = s_cnt[c1], o1 = s_off[c1];
        float a0 = 0.0f, a1 = 0.0f;
        const int nm = (n0 > n1) ? n0 : n1;
        for (int j = 0; j < nm; ++j) {
            if (j < n0) a0 += s_x[s_list[o0 + j] * ND + lane];
            if (j < n1) a1 += s_x[s_list[o1 + j] * ND + lane];
        }
        __builtin_nontemporal_store(a0 * s_inv[c0], &oe[c0 * ND + lane]);
        __builtin_nontemporal_store(a1 * s_inv[c1], &oe[c1 * ND + lane]);
    }
}

extern "C" void kernel_launch(void* const* d_in, const int* in_sizes, int n_in,
                              void* d_out, int out_size, void* d_ws, size_t ws_size,
                              hipStream_t stream) {
    const float* x      = (const float*)d_in[0];  // [B,S,D] f32
    const int*   labels = (const int*)  d_in[1];  // [B,S]   i32
    const int*   amask  = (const int*)  d_in[2];  // [B,S]   i32

    float* out_emb  = (float*)d_out;                          // [B,C,D]
    float* out_mask = out_emb + (size_t)NB * NC * ND;         // [B,C,S]

    s3rec_cluster_kernel<<<dim3(NB * 3), dim3(256), 0, stream>>>(
        x, labels, amask, out_emb, out_mask);
}

// Round 3
// 326.770 us; speedup vs baseline: 1.0261x; 1.0261x over previous
//
#include <hip/hip_runtime.h>

// Problem constants (from reference):
//   B=1024 batches, S=200 seq, D=64 dim, C=256 clusters
// Outputs (concat in d_out, all read back as float32):
//   out[0] cluster_emb  [B,C,D] = 16,777,216 f32
//   out[1] cluster_mask [B,C,S] = 52,428,800 f32 (0.0/1.0 values)
//
// Role-split blocks, 3 per batch:
//   role 0,1: stream one half of cluster_mask[b] (store-bound, PLAIN vec4
//             stores — R2 post-mortem: nontemporal stores bypass the L2
//             write-combining path; the 6.4 TB/s fill kernel uses plain
//             stores. nt was the one untested constant across all slow
//             versions).
//   role 2:   counting-sort CSR + register accumulation; x reads are
//             L3-resident (52 MB total), so no LDS staging of x.
// LDS ~4.7 KB -> high residency; mask (store-bound) and emb (latency-ish)
// blocks co-schedule on each CU.
#define NB 1024
#define NS 200
#define ND 64
#define NC 256

typedef float v4f __attribute__((ext_vector_type(4)));

__global__ __launch_bounds__(256, 8) void s3rec_cluster_kernel(
    const float* __restrict__ x,       // [B,S,D]
    const int*   __restrict__ labels,  // [B,S]
    const int*   __restrict__ amask,   // [B,S]
    float* __restrict__ out_emb,       // [B,C,D]
    float* __restrict__ out_mask)      // [B,C,S]
{
    __shared__ __align__(16) int s_lab[NS];  // label if masked else -1
    __shared__ int   s_cnt[NC];
    __shared__ int   s_off[NC];
    __shared__ float s_inv[NC];
    __shared__ int   s_list[NS];             // seq idx grouped by cluster
    __shared__ int   s_part[4];

    const int role = blockIdx.x % 3;   // 0,1 = mask halves; 2 = emb
    const int b    = blockIdx.x / 3;
    const int t    = threadIdx.x;

    // --- stage labels packed with mask ---
    for (int i = t; i < NS; i += 256) {
        const int l = labels[b * NS + i];
        const int m = amask [b * NS + i];
        s_lab[i] = (m != 0) ? l : -1;
    }

    if (role < 2) {
        // ---------------- mask writer: half of [C,S] = 6400 vec4 ----------
        __syncthreads();
        v4f* om4 = reinterpret_cast<v4f*>(out_mask + (size_t)b * (NC * NS));
        const int i4lo = role * 6400;
        #pragma unroll 5
        for (int k = 0; k < 25; ++k) {
            const int i4 = i4lo + k * 256 + t;
            const int c  = i4 / 50;
            const int s0 = (i4 - c * 50) * 4;      // 16B aligned
            const int4 lv = *reinterpret_cast<const int4*>(&s_lab[s0]);
            v4f v;
            v.x = (lv.x == c) ? 1.0f : 0.0f;
            v.y = (lv.y == c) ? 1.0f : 0.0f;
            v.z = (lv.z == c) ? 1.0f : 0.0f;
            v.w = (lv.w == c) ? 1.0f : 0.0f;
            om4[i4] = v;                            // plain store (L2 WB path)
        }
        return;
    }

    // ---------------- emb computer ---------------------------------------
    // 1) histogram (t indexes clusters exactly: NC == 256)
    s_cnt[t] = 0;
    __syncthreads();
    if (t < NS) {
        const int l = s_lab[t];
        if (l >= 0) atomicAdd(&s_cnt[l], 1);
    }
    __syncthreads();

    // 2) inverse counts + exclusive prefix scan over 256 counts
    const int lane = t & 63;
    const int w    = t >> 6;
    const int cnt  = s_cnt[t];
    s_inv[t] = (cnt > 0) ? (1.0f / (float)cnt) : 0.0f;

    int v = cnt;                                  // wave-inclusive scan
    #pragma unroll
    for (int d = 1; d < 64; d <<= 1) {
        const int n = __shfl_up(v, d, 64);
        if (lane >= d) v += n;
    }
    if (lane == 63) s_part[w] = v;
    __syncthreads();
    int base = 0;
    for (int i = 0; i < w; ++i) base += s_part[i];
    s_off[t] = base + v - cnt;                    // exclusive offset
    __syncthreads();

    // 3) deterministic scatter: rank = #earlier same-label entries, so each
    //    cluster's list is ascending in s (matches reference sum order).
    if (t < NS) {
        const int L = s_lab[t];
        if (L >= 0) {
            int r = 0;
            for (int s2 = 0; s2 < t; ++s2) r += (s_lab[s2] == L) ? 1 : 0;
            s_list[s_off[L] + r] = t;
        }
    }
    __syncthreads();

    // 4) accumulate per cluster in registers, 2 clusters in flight per wave
    //    (c wave-uniform, lane = d). x row read = 256B coalesced, L3-hit.
    const float* xb = x + (size_t)b * NS * ND;
    float* oe = out_emb + (size_t)b * (NC * ND);
    for (int cc = 0; cc < 64; cc += 2) {
        const int c0 = w * 64 + cc;
        const int c1 = c0 + 1;
        const int n0 = s_cnt[c0], o0 = s_off[c0];
        const int n1 = s_cnt[c1], o1 = s_off[c1];
        float a0 = 0.0f, a1 = 0.0f;
        const int nm = (n0 > n1) ? n0 : n1;
        for (int j = 0; j < nm; ++j) {
            if (j < n0) a0 += xb[s_list[o0 + j] * ND + lane];
            if (j < n1) a1 += xb[s_list[o1 + j] * ND + lane];
        }
        oe[c0 * ND + lane] = a0 * s_inv[c0];      // plain stores
        oe[c1 * ND + lane] = a1 * s_inv[c1];
    }
}

extern "C" void kernel_launch(void* const* d_in, const int* in_sizes, int n_in,
                              void* d_out, int out_size, void* d_ws, size_t ws_size,
                              hipStream_t stream) {
    const float* x      = (const float*)d_in[0];  // [B,S,D] f32
    const int*   labels = (const int*)  d_in[1];  // [B,S]   i32
    const int*   amask  = (const int*)  d_in[2];  // [B,S]   i32

    float* out_emb  = (float*)d_out;                          // [B,C,D]
    float* out_mask = out_emb + (size_t)NB * NC * ND;         // [B,C,S]

    s3rec_cluster_kernel<<<dim3(NB * 3), dim3(256), 0, stream>>>(
        x, labels, amask, out_emb, out_mask);
}

// Round 4
// 320.966 us; speedup vs baseline: 1.0447x; 1.0181x over previous
//
#include <hip/hip_runtime.h>

// Problem constants (from reference):
//   B=1024 batches, S=200 seq, D=64 dim, C=256 clusters
// Outputs (concat in d_out, all read back as float32):
//   out[0] cluster_emb  [B,C,D] = 16,777,216 f32
//   out[1] cluster_mask [B,C,S] = 52,428,800 f32 (0.0/1.0 values)
//
// Structure (R4): 2 blocks per batch, each fully balanced (132 KB stores):
//   1) build counting-sort CSR in LDS (histogram -> scan -> rank scatter)
//   2) fire-and-forget one half of cluster_mask[b] (25x vec4/thread)
//   3) compute 128 clusters of cluster_emb from registers while the mask
//      stores drain — NO __syncthreads after the stores, so the compiler's
//      vmcnt(0)-before-s_barrier drain never serializes store-drain with
//      the gather compute.
// x reads are L3-resident (52 MB total). LDS ~4.7 KB; launch_bounds(256,4)
// keeps VGPR cap at 128 (no spill risk in the 4-chain gather).
#define NB 1024
#define NS 200
#define ND 64
#define NC 256

typedef float v4f __attribute__((ext_vector_type(4)));

__global__ __launch_bounds__(256, 4) void s3rec_cluster_kernel(
    const float* __restrict__ x,       // [B,S,D]
    const int*   __restrict__ labels,  // [B,S]
    const int*   __restrict__ amask,   // [B,S]
    float* __restrict__ out_emb,       // [B,C,D]
    float* __restrict__ out_mask)      // [B,C,S]
{
    __shared__ __align__(16) int s_lab[NS];  // label if masked else -1
    __shared__ int   s_cnt[NC];
    __shared__ int   s_off[NC];
    __shared__ float s_inv[NC];
    __shared__ int   s_list[NS];             // seq idx grouped by cluster
    __shared__ int   s_part[4];

    const int half = blockIdx.x & 1;   // which half of [C] this block owns
    const int b    = blockIdx.x >> 1;
    const int t    = threadIdx.x;

    // --- stage labels packed with mask; zero histogram ---
    if (t < NS) {
        const int l = labels[b * NS + t];
        const int m = amask [b * NS + t];
        s_lab[t] = (m != 0) ? l : -1;
    }
    s_cnt[t] = 0;
    __syncthreads();

    // --- 1) histogram (t indexes clusters exactly: NC == 256) ---
    if (t < NS) {
        const int l = s_lab[t];
        if (l >= 0) atomicAdd(&s_cnt[l], 1);
    }
    __syncthreads();

    // --- 2) inverse counts + exclusive prefix scan over 256 counts ---
    const int lane = t & 63;
    const int w    = t >> 6;
    const int cnt  = s_cnt[t];
    s_inv[t] = (cnt > 0) ? (1.0f / (float)cnt) : 0.0f;

    int v = cnt;                                  // wave-inclusive scan
    #pragma unroll
    for (int d = 1; d < 64; d <<= 1) {
        const int n = __shfl_up(v, d, 64);
        if (lane >= d) v += n;
    }
    if (lane == 63) s_part[w] = v;
    __syncthreads();
    int base = 0;
    for (int i = 0; i < w; ++i) base += s_part[i];
    s_off[t] = base + v - cnt;                    // exclusive offset
    __syncthreads();

    // --- 3) deterministic scatter: rank = #earlier same-label entries, so
    //        each cluster's list is ascending in s (matches ref sum order).
    if (t < NS) {
        const int L = s_lab[t];
        if (L >= 0) {
            int r = 0;
            for (int s2 = 0; s2 < t; ++s2) r += (s_lab[s2] == L) ? 1 : 0;
            s_list[s_off[L] + r] = t;
        }
    }
    __syncthreads();   // last barrier of the kernel (before any global store)

    // --- 4) mask half [half*128 .. half*128+128) x [S]: 6400 vec4, issued
    //        fire-and-forget; they drain during step 5's gather compute.
    v4f* om4 = reinterpret_cast<v4f*>(out_mask + (size_t)b * (NC * NS));
    const int i4lo = half * 6400;
    #pragma unroll 5
    for (int k = 0; k < 25; ++k) {
        const int i4 = i4lo + k * 256 + t;
        const int c  = i4 / 50;
        const int s0 = (i4 - c * 50) * 4;          // 16B aligned
        const int4 lv = *reinterpret_cast<const int4*>(&s_lab[s0]);
        v4f mv;
        mv.x = (lv.x == c) ? 1.0f : 0.0f;
        mv.y = (lv.y == c) ? 1.0f : 0.0f;
        mv.z = (lv.z == c) ? 1.0f : 0.0f;
        mv.w = (lv.w == c) ? 1.0f : 0.0f;
        om4[i4] = mv;
    }

    // --- 5) emb for this half's 128 clusters: 32 clusters/wave, 4 chains
    //        in flight (c wave-uniform, lane = d; x row = 256B coalesced,
    //        L3-hit ~200-300cy, hidden by the 4 independent chains).
    const float* xb = x + (size_t)b * NS * ND;
    float* oe = out_emb + (size_t)b * (NC * ND);
    const int cbase = half * 128 + w * 32;
    for (int cc = 0; cc < 32; cc += 4) {
        const int c0 = cbase + cc;
        const int n0 = s_cnt[c0 + 0], o0 = s_off[c0 + 0];
        const int n1 = s_cnt[c0 + 1], o1 = s_off[c0 + 1];
        const int n2 = s_cnt[c0 + 2], o2 = s_off[c0 + 2];
        const int n3 = s_cnt[c0 + 3], o3 = s_off[c0 + 3];
        float a0 = 0.0f, a1 = 0.0f, a2 = 0.0f, a3 = 0.0f;
        int nm = n0;
        nm = (n1 > nm) ? n1 : nm;
        nm = (n2 > nm) ? n2 : nm;
        nm = (n3 > nm) ? n3 : nm;
        for (int j = 0; j < nm; ++j) {
            if (j < n0) a0 += xb[s_list[o0 + j] * ND + lane];
            if (j < n1) a1 += xb[s_list[o1 + j] * ND + lane];
            if (j < n2) a2 += xb[s_list[o2 + j] * ND + lane];
            if (j < n3) a3 += xb[s_list[o3 + j] * ND + lane];
        }
        oe[(c0 + 0) * ND + lane] = a0 * s_inv[c0 + 0];
        oe[(c0 + 1) * ND + lane] = a1 * s_inv[c0 + 1];
        oe[(c0 + 2) * ND + lane] = a2 * s_inv[c0 + 2];
        oe[(c0 + 3) * ND + lane] = a3 * s_inv[c0 + 3];
    }
}

extern "C" void kernel_launch(void* const* d_in, const int* in_sizes, int n_in,
                              void* d_out, int out_size, void* d_ws, size_t ws_size,
                              hipStream_t stream) {
    const float* x      = (const float*)d_in[0];  // [B,S,D] f32
    const int*   labels = (const int*)  d_in[1];  // [B,S]   i32
    const int*   amask  = (const int*)  d_in[2];  // [B,S]   i32

    float* out_emb  = (float*)d_out;                          // [B,C,D]
    float* out_mask = out_emb + (size_t)NB * NC * ND;         // [B,C,S]

    s3rec_cluster_kernel<<<dim3(NB * 2), dim3(256), 0, stream>>>(
        x, labels, amask, out_emb, out_mask);
}